// Round 8
// baseline (84.065 us; speedup 1.0000x reference)
//
#include <hip/hip_runtime.h>

typedef __attribute__((ext_vector_type(2))) float f32x2;

#define NS 1024      // N samples
#define MM 64        // M patches
#define CC 4         // C compartments
#define NSTEPS 100
#define CLIPMAX 1e10f

#if __has_attribute(amdgpu_num_agpr)
#define NO_AGPR __attribute__((amdgpu_num_agpr(0)))
#else
#define NO_AGPR
#endif

// Broadcast lane k's value to all lanes via v_readlane (setup only).
__device__ __forceinline__ float rdlane(float v, int k) {
    return __uint_as_float(__builtin_amdgcn_readlane(__float_as_uint(v), k));
}
// Force a (wave-uniform) value into an SGPR.
__device__ __forceinline__ float sfirst(float v) {
    return __uint_as_float(__builtin_amdgcn_readfirstlane(__float_as_uint(v)));
}

// One wave per sample, BARRIER-FREE (r3/r7 structure). Phase B's p-broadcast
// goes through LDS with NO barrier: within a single wave, DS ops are ordered
// by lgkmcnt (compiler-inserted) -- r4's mistake was __syncthreads(), whose
// semantics force s_waitcnt vmcnt(0), i.e. a per-step drain of the trajectory
// global store. 16x ds_read_b128 broadcast reads (conflict-free) replace 64x
// v_readlane + VALU->SGPR hazards. amdgpu_num_agpr(0) forces plain VGPR homes
// for the pinned state (r3-r7: allocator parked it in AGPRs, VGPR_Count ~84,
// with v_accvgpr ping-pong inflating issue).
__global__ __launch_bounds__(64, 1) NO_AGPR void metapop_kernel(
    const float* __restrict__ R,     // (NS, MM, MM)
    const float* __restrict__ T,     // (NS, CC, CC)
    const float* __restrict__ rho0,  // (NS, MM, CC)
    const float* __restrict__ beta,  // (NS,)
    float* __restrict__ out)         // (NSTEPS, NS, MM, CC)
{
    const int n    = blockIdx.x;
    const int lane = threadIdx.x;    // 0..63

    __shared__ float pbuf[MM];

    const float* Rn = R + (size_t)n * (MM * MM);

    // opaque zero in an SGPR (keeps Rrow/Gcol as non-rematerializable values)
    float fz;
    asm volatile("s_mov_b32 %0, 0" : "=s"(fz));

    // ---- Rrow pairs: Rrow[k2] = (R[n,lane,2k2], R[n,lane,2k2+1]) ----
    f32x2 Rrow[32];
    {
        const float4* p4 = (const float4*)(Rn + lane * MM);
        #pragma unroll
        for (int q = 0; q < 16; ++q) {
            float4 v = p4[q];
            Rrow[2*q]   = (f32x2){v.x + fz, v.y + fz};
            Rrow[2*q+1] = (f32x2){v.z + fz, v.w + fz};
        }
    }

    // ---- ntot[lane] = sum_i R[n,i,lane] (coalesced per i; L1/L2-hot) ----
    float nt = 0.f;
    #pragma unroll
    for (int i = 0; i < MM; ++i) nt += Rn[i * MM + lane];
    const float binv = beta[n] / nt;   // lane j holds beta/ntot[j]

    // ---- Gcol pairs via the transpose bijection ----
    // Rt[n,i,j] = R[(i&15)*64+j, (n&15)*4+(i>>4), n>>4]
    f32x2 Gcol[32];
    {
        const int q     = n >> 4;
        const int a     = ((n & 15) << 2) + (lane >> 4);
        const int sbase = (lane & 15) << 6;
        #pragma unroll
        for (int j2 = 0; j2 < 32; ++j2) {
            const int j0 = 2 * j2, j1 = 2 * j2 + 1;
            float v0 = R[(size_t)(sbase + j0) * (MM * MM) + a * MM + q];
            float v1 = R[(size_t)(sbase + j1) * (MM * MM) + a * MM + q];
            Gcol[j2] = (f32x2){v0 * rdlane(binv, j0) + fz,
                               v1 * rdlane(binv, j1) + fz};
        }
    }

    // ---- T[n]: wave-uniform -> SGPRs ----
    float tt[CC][CC];
    {
        const float* Tn = T + n * (CC * CC);
        #pragma unroll
        for (int k = 0; k < CC; ++k)
            #pragma unroll
            for (int l = 0; l < CC; ++l)
                tt[k][l] = sfirst(Tn[k * CC + l]);
    }

    // ---- rho0 ----
    float rh[CC];
    {
        float4 v = *(const float4*)(rho0 + (size_t)n * (MM * CC) + lane * CC);
        rh[0] = v.x; rh[1] = v.y; rh[2] = v.z; rh[3] = v.w;
    }

    float* ob = out + (size_t)n * (MM * CC) + lane * CC;
    const size_t stride = (size_t)NS * MM * CC;

    for (int step = 0; step < NSTEPS; ++step) {
        // trajectory records PRE-update state; coalesced float4, fire-and-forget
        *(float4*)(ob + (size_t)step * stride) =
            make_float4(rh[0], rh[1], rh[2], rh[3]);

        // phase A (lane = i): p = 1 - prod_j (1 - rho1*Gcol[j]); packed, 4 chains
        const float r1  = rh[1];
        const f32x2 r1v = {r1, r1};
        const f32x2 one = {1.f, 1.f};
        f32x2 pa = one, pb = one, pc = one, pd = one;
        #pragma unroll
        for (int j2 = 0; j2 < 8; ++j2) {
            pa *= one - r1v * Gcol[j2];
            pb *= one - r1v * Gcol[j2 + 8];
            pc *= one - r1v * Gcol[j2 + 16];
            pd *= one - r1v * Gcol[j2 + 24];
        }
        const f32x2 pq = (pa * pb) * (pc * pd);
        const float p  = 1.f - pq.x * pq.y;

        // p-broadcast via LDS, NO barrier (single wave: lgkmcnt orders DS ops)
        pbuf[lane] = p;

        // phase B (lane = j): s = sum_k Rrow[k]*p[k]; 16x b128 broadcast reads
        float s0 = 0.f, s1 = 0.f, s2 = 0.f, s3 = 0.f;
        {
            const float4* pb4 = (const float4*)pbuf;
            #pragma unroll
            for (int q = 0; q < 4; ++q) {
                float4 pv; f32x2 rA, rB;
                pv = pb4[q];                               // k = 4q .. 4q+3
                rA = Rrow[2*q];      rB = Rrow[2*q + 1];
                s0 += rA.x * pv.x + rA.y * pv.y + rB.x * pv.z + rB.y * pv.w;
                pv = pb4[q + 4];                           // k = 16+4q ..
                rA = Rrow[2*q + 8];  rB = Rrow[2*q + 9];
                s1 += rA.x * pv.x + rA.y * pv.y + rB.x * pv.z + rB.y * pv.w;
                pv = pb4[q + 8];                           // k = 32+4q ..
                rA = Rrow[2*q + 16]; rB = Rrow[2*q + 17];
                s2 += rA.x * pv.x + rA.y * pv.y + rB.x * pv.z + rB.y * pv.w;
                pv = pb4[q + 12];                          // k = 48+4q ..
                rA = Rrow[2*q + 24]; rB = Rrow[2*q + 25];
                s3 += rA.x * pv.x + rA.y * pv.y + rB.x * pv.z + rB.y * pv.w;
            }
        }
        const float ssum = (s0 + s1) + (s2 + s3);
        const float sr   = (rh[0] + rh[1]) + (rh[2] + rh[3]);
        const float ninf = (1.f - sr) * ssum;

        // phase C (lane-local): rho_new[l] = sum_k rho[k]*T[k,l] (+ninf at l=0)
        float nr[CC];
        #pragma unroll
        for (int l = 0; l < CC; ++l) {
            float v = rh[0] * tt[0][l] + rh[1] * tt[1][l]
                    + rh[2] * tt[2][l] + rh[3] * tt[3][l];
            if (l == 0) v += ninf;
            nr[l] = fminf(fmaxf(v, 0.f), CLIPMAX);
        }
        #pragma unroll
        for (int l = 0; l < CC; ++l) rh[l] = nr[l];
    }
}

extern "C" void kernel_launch(void* const* d_in, const int* in_sizes, int n_in,
                              void* d_out, int out_size, void* d_ws, size_t ws_size,
                              hipStream_t stream) {
    const float* R    = (const float*)d_in[0];
    const float* T    = (const float*)d_in[1];
    const float* rho0 = (const float*)d_in[2];
    const float* beta = (const float*)d_in[3];
    float* out = (float*)d_out;
    hipLaunchKernelGGL(metapop_kernel, dim3(NS), dim3(64), 0, stream,
                       R, T, rho0, beta, out);
}